// Round 1
// baseline (8420.509 us; speedup 1.0000x reference)
//
#include <hip/hip_runtime.h>
#include <math.h>

// Problem constants
constexpr int Vv = 50257;
constexpr int Dd = 512;
constexpr int Hh = 8;
constexpr int Ll = 6;
constexpr int Ss = 1024;
constexpr int Bb = 2;
constexpr int Dh = 64;          // head dim
constexpr int NT = Bb * Ss;     // 2048 token rows
constexpr int Dff = 4 * Dd;     // 2048
// NOTE: reference scales by sqrt(D)=sqrt(512), NOT sqrt(head_dim)
constexpr float INV_SCALE = 0.04419417382415922f; // 1/sqrt(512)

__device__ inline float wave_sum(float x) {
#pragma unroll
  for (int off = 32; off > 0; off >>= 1) x += __shfl_xor(x, off, 64);
  return x;
}
__device__ inline float wave_max(float x) {
#pragma unroll
  for (int off = 32; off > 0; off >>= 1) x = fmaxf(x, __shfl_xor(x, off, 64));
  return x;
}

// x[b,s,:] = (tok_emb[inputs[b,s]] + pos_emb[s]) * mask
__global__ void embed_kernel(const int* __restrict__ idx, const int* __restrict__ masks,
                             const float* __restrict__ tok, const float* __restrict__ pos,
                             float* __restrict__ x) {
  int i = blockIdx.x * blockDim.x + threadIdx.x;
  if (i >= NT * Dd) return;
  int d = i & (Dd - 1);
  int row = i >> 9;            // / 512
  int s = row & (Ss - 1);
  int b = row >> 10;
  int t = idx[b * (Ss + 1) + s];
  float m = (float)masks[row];
  x[i] = (tok[(size_t)t * Dd + d] + pos[s * Dd + d]) * m;
}

// one wave per row, D=512 -> 8 elems/lane
__global__ __launch_bounds__(64) void ln_kernel(const float* __restrict__ x,
                                                const float* __restrict__ g,
                                                const float* __restrict__ b,
                                                float* __restrict__ out) {
  int row = blockIdx.x;
  int lane = threadIdx.x;
  const float* xr = x + (size_t)row * Dd;
  float vals[8];
  float s = 0.f;
#pragma unroll
  for (int i = 0; i < 8; i++) { vals[i] = xr[lane + i * 64]; s += vals[i]; }
  s = wave_sum(s);
  float mean = s * (1.f / Dd);
  float vs = 0.f;
#pragma unroll
  for (int i = 0; i < 8; i++) { float dd = vals[i] - mean; vs += dd * dd; }
  vs = wave_sum(vs);
  float rstd = rsqrtf(vs * (1.f / Dd) + 1e-5f);
  float* orow = out + (size_t)row * Dd;
#pragma unroll
  for (int i = 0; i < 8; i++) {
    int d = lane + i * 64;
    orow[d] = (vals[i] - mean) * rstd * g[d] + b[d];
  }
}

// C[m,n] = (opt resid[m,n]) + act( sum_k A[m,k] W[k,n] + bias[n] )
// 64x64 tile, 256 threads, 4x4 microtile, BK=16. M must be a multiple of 64 (true here: 2048).
__global__ __launch_bounds__(256) void gemm_kernel(const float* __restrict__ A,
                                                   const float* __restrict__ W,
                                                   const float* __restrict__ bias,
                                                   const float* __restrict__ resid,
                                                   float* __restrict__ C,
                                                   int M, int N, int K, int act) {
  __shared__ float As[64][17];
  __shared__ float Bs[16][64];
  int t = threadIdx.x;
  int tx = t & 15, ty = t >> 4;
  int m0 = blockIdx.y * 64, n0 = blockIdx.x * 64;
  int aRow = t >> 2, aCol = (t & 3) * 4;
  int bRow = t >> 4, bCol = (t & 15) * 4;
  float acc[4][4] = {};
  bool bAligned = ((N & 3) == 0) && (n0 + 64 <= N);
  for (int k0 = 0; k0 < K; k0 += 16) {
    float4 av = *(const float4*)(A + (size_t)(m0 + aRow) * K + (k0 + aCol));
    As[aRow][aCol + 0] = av.x; As[aRow][aCol + 1] = av.y;
    As[aRow][aCol + 2] = av.z; As[aRow][aCol + 3] = av.w;
    if (bAligned) {
      float4 bv = *(const float4*)(W + (size_t)(k0 + bRow) * N + (n0 + bCol));
      Bs[bRow][bCol + 0] = bv.x; Bs[bRow][bCol + 1] = bv.y;
      Bs[bRow][bCol + 2] = bv.z; Bs[bRow][bCol + 3] = bv.w;
    } else {
#pragma unroll
      for (int j = 0; j < 4; j++) {
        int c = n0 + bCol + j;
        Bs[bRow][bCol + j] = (c < N) ? W[(size_t)(k0 + bRow) * N + c] : 0.f;
      }
    }
    __syncthreads();
#pragma unroll
    for (int kk = 0; kk < 16; kk++) {
      float a0 = As[ty * 4 + 0][kk], a1 = As[ty * 4 + 1][kk];
      float a2 = As[ty * 4 + 2][kk], a3 = As[ty * 4 + 3][kk];
      float b0 = Bs[kk][tx * 4 + 0], b1v = Bs[kk][tx * 4 + 1];
      float b2v = Bs[kk][tx * 4 + 2], b3v = Bs[kk][tx * 4 + 3];
      acc[0][0] += a0 * b0;  acc[0][1] += a0 * b1v; acc[0][2] += a0 * b2v; acc[0][3] += a0 * b3v;
      acc[1][0] += a1 * b0;  acc[1][1] += a1 * b1v; acc[1][2] += a1 * b2v; acc[1][3] += a1 * b3v;
      acc[2][0] += a2 * b0;  acc[2][1] += a2 * b1v; acc[2][2] += a2 * b2v; acc[2][3] += a2 * b3v;
      acc[3][0] += a3 * b0;  acc[3][1] += a3 * b1v; acc[3][2] += a3 * b2v; acc[3][3] += a3 * b3v;
    }
    __syncthreads();
  }
#pragma unroll
  for (int i = 0; i < 4; i++) {
    int row = m0 + ty * 4 + i;
#pragma unroll
    for (int j = 0; j < 4; j++) {
      int col = n0 + tx * 4 + j;
      if (col < N) {
        float vsum = acc[i][j] + (bias ? bias[col] : 0.f);
        if (act == 1) vsum = 0.5f * vsum * (1.f + erff(vsum * 0.70710678118654752f));
        if (resid) vsum += resid[(size_t)row * N + col];
        C[(size_t)row * N + col] = vsum;
      }
    }
  }
}

// Flash-style attention: one wave per (b, h, qrow). Online softmax over key chunks of 64.
// q,k,v stored [B, S, D] with head h at columns h*64..h*64+63.
__global__ __launch_bounds__(64) void attn_kernel(const float* __restrict__ q,
                                                  const float* __restrict__ k,
                                                  const float* __restrict__ v,
                                                  float* __restrict__ o) {
  __shared__ float kbuf[64 * 65];
  __shared__ float vbuf[64 * 65];
  __shared__ float qsh[64];
  __shared__ float psh[64];
  int lane = threadIdx.x;
  int bid = blockIdx.x;
  int qrow = bid & (Ss - 1);
  int h = (bid >> 10) & (Hh - 1);
  int b = bid >> 13;
  const size_t base = ((size_t)b * Ss) * Dd + h * Dh;  // + s*Dd
  float qv = q[base + (size_t)qrow * Dd + lane];
  qsh[lane] = qv;
  float mval = -INFINITY, lsum = 0.f, acc = 0.f;
  for (int j0 = 0; j0 <= qrow; j0 += 64) {
    __syncthreads();  // protect kbuf/vbuf/psh reuse; publish qsh on first iter
#pragma unroll 8
    for (int i = 0; i < 64; i++) {
      kbuf[i * 65 + lane] = k[base + (size_t)(j0 + i) * Dd + lane];
      vbuf[i * 65 + lane] = v[base + (size_t)(j0 + i) * Dd + lane];
    }
    __syncthreads();
    float dot = 0.f;
#pragma unroll
    for (int d = 0; d < 64; d++) dot += kbuf[lane * 65 + d] * qsh[d];
    int j = j0 + lane;
    float sv = (j <= qrow) ? dot * INV_SCALE : -INFINITY;
    float cmax = wave_max(sv);
    float newm = fmaxf(mval, cmax);
    float p = expf(sv - newm);       // 0 for masked lanes
    float alpha = expf(mval - newm); // 0 on first chunk
    lsum = lsum * alpha + wave_sum(p);
    psh[lane] = p;
    acc *= alpha;
    __syncthreads();
#pragma unroll 8
    for (int jj = 0; jj < 64; jj++) acc += psh[jj] * vbuf[jj * 65 + lane];
    mval = newm;
  }
  o[base + (size_t)qrow * Dd + lane] = acc / lsum;
}

// per-row NLL: logsumexp over V, minus target logit
__global__ __launch_bounds__(256) void nll_kernel(const float* __restrict__ logits,
                                                  const int* __restrict__ idx,
                                                  const int* __restrict__ masks,
                                                  float* __restrict__ row_nll) {
  __shared__ float red[256];
  int row = blockIdx.x;
  int b = row >> 10, s = row & (Ss - 1);
  const float* lr = logits + (size_t)row * Vv;
  float mx = -INFINITY;
  for (int j = threadIdx.x; j < Vv; j += 256) mx = fmaxf(mx, lr[j]);
  red[threadIdx.x] = mx;
  __syncthreads();
  for (int st = 128; st > 0; st >>= 1) {
    if (threadIdx.x < st) red[threadIdx.x] = fmaxf(red[threadIdx.x], red[threadIdx.x + st]);
    __syncthreads();
  }
  mx = red[0];
  __syncthreads();
  float sum = 0.f;
  for (int j = threadIdx.x; j < Vv; j += 256) sum += expf(lr[j] - mx);
  red[threadIdx.x] = sum;
  __syncthreads();
  for (int st = 128; st > 0; st >>= 1) {
    if (threadIdx.x < st) red[threadIdx.x] += red[threadIdx.x + st];
    __syncthreads();
  }
  if (threadIdx.x == 0) {
    int target = idx[b * (Ss + 1) + s + 1];
    float nll = logf(red[0]) + mx - lr[target];
    row_nll[row] = nll * (float)masks[row];
  }
}

__global__ __launch_bounds__(256) void loss_reduce_kernel(const float* __restrict__ row_nll,
                                                          float* __restrict__ out_loss) {
  __shared__ float red[256];
  float s = 0.f;
  for (int i = threadIdx.x; i < NT; i += 256) s += row_nll[i];
  red[threadIdx.x] = s;
  __syncthreads();
  for (int st = 128; st > 0; st >>= 1) {
    if (threadIdx.x < st) red[threadIdx.x] += red[threadIdx.x + st];
    __syncthreads();
  }
  if (threadIdx.x == 0) out_loss[0] = red[0] * (1.f / NT);
}

extern "C" void kernel_launch(void* const* d_in, const int* in_sizes, int n_in,
                              void* d_out, int out_size, void* d_ws, size_t ws_size,
                              hipStream_t stream) {
  const int*   idx   = (const int*)d_in[0];
  const int*   masks = (const int*)d_in[1];
  const float* tok   = (const float*)d_in[2];
  const float* pos   = (const float*)d_in[3];
  const float* Wq    = (const float*)d_in[4];
  const float* bq    = (const float*)d_in[5];
  const float* Wk    = (const float*)d_in[6];
  const float* bk    = (const float*)d_in[7];
  const float* Wv    = (const float*)d_in[8];
  const float* bv    = (const float*)d_in[9];
  const float* Wo    = (const float*)d_in[10];
  const float* bo    = (const float*)d_in[11];
  const float* ln1g  = (const float*)d_in[12];
  const float* ln1b  = (const float*)d_in[13];
  const float* W1    = (const float*)d_in[14];
  const float* b1    = (const float*)d_in[15];
  const float* W2    = (const float*)d_in[16];
  const float* b2    = (const float*)d_in[17];
  const float* ln2g  = (const float*)d_in[18];
  const float* ln2b  = (const float*)d_in[19];
  const float* lnfg  = (const float*)d_in[20];
  const float* lnfb  = (const float*)d_in[21];
  const float* headw = (const float*)d_in[22];

  float* out = (float*)d_out;
  float* ws = (float*)d_ws;

  // workspace layout (floats): ~42 MB total
  const size_t NTD = (size_t)NT * Dd;        // 1,048,576
  float* x    = ws;
  float* h    = x + NTD;
  float* qb   = h + NTD;
  float* kb   = qb + NTD;
  float* vb   = kb + NTD;
  float* ob   = vb + NTD;
  float* mlp  = ob + NTD;                    // NT * Dff = 4,194,304
  float* rnll = mlp + (size_t)NT * Dff;      // NT floats

  embed_kernel<<<(NT * Dd + 255) / 256, 256, 0, stream>>>(idx, masks, tok, pos, x);

  const size_t DD = (size_t)Dd * Dd;
  for (int l = 0; l < Ll; l++) {
    ln_kernel<<<NT, 64, 0, stream>>>(x, ln1g + (size_t)l * Dd, ln1b + (size_t)l * Dd, h);
    dim3 g512((Dd + 63) / 64, NT / 64);
    gemm_kernel<<<g512, 256, 0, stream>>>(h, Wq + l * DD, bq + (size_t)l * Dd, nullptr, qb, NT, Dd, Dd, 0);
    gemm_kernel<<<g512, 256, 0, stream>>>(h, Wk + l * DD, bk + (size_t)l * Dd, nullptr, kb, NT, Dd, Dd, 0);
    gemm_kernel<<<g512, 256, 0, stream>>>(h, Wv + l * DD, bv + (size_t)l * Dd, nullptr, vb, NT, Dd, Dd, 0);
    attn_kernel<<<Bb * Hh * Ss, 64, 0, stream>>>(qb, kb, vb, ob);
    gemm_kernel<<<g512, 256, 0, stream>>>(ob, Wo + l * DD, bo + (size_t)l * Dd, x, x, NT, Dd, Dd, 0);
    ln_kernel<<<NT, 64, 0, stream>>>(x, ln2g + (size_t)l * Dd, ln2b + (size_t)l * Dd, h);
    dim3 gff((Dff + 63) / 64, NT / 64);
    gemm_kernel<<<gff, 256, 0, stream>>>(h, W1 + (size_t)l * Dd * Dff, b1 + (size_t)l * Dff, nullptr, mlp, NT, Dff, Dd, 1);
    gemm_kernel<<<g512, 256, 0, stream>>>(mlp, W2 + (size_t)l * Dff * Dd, b2 + (size_t)l * Dd, x, x, NT, Dd, Dff, 0);
  }

  ln_kernel<<<NT, 64, 0, stream>>>(x, lnfg, lnfb, h);
  dim3 ghead((Vv + 63) / 64, NT / 64);
  gemm_kernel<<<ghead, 256, 0, stream>>>(h, headw, nullptr, nullptr, out, NT, Vv, Dd, 0);

  nll_kernel<<<NT, 256, 0, stream>>>(out, idx, masks, rnll);
  loss_reduce_kernel<<<1, 256, 0, stream>>>(rnll, out + (size_t)NT * Vv);
}

// Round 2
// 3373.156 us; speedup vs baseline: 2.4963x; 2.4963x over previous
//
#include <hip/hip_runtime.h>
#include <hip/hip_bf16.h>
#include <math.h>

constexpr int Vv   = 50257;
constexpr int Vpad = 50304;          // 393 * 128
constexpr int Dd   = 512;
constexpr int Hh   = 8;
constexpr int Ll   = 6;
constexpr int Ss   = 1024;
constexpr int Bb   = 2;
constexpr int NT   = Bb * Ss;        // 2048
constexpr int Dff  = 2048;
constexpr float INV_SCALE = 0.04419417382415922f; // 1/sqrt(512)

typedef __hip_bfloat16 bf16;
typedef __attribute__((ext_vector_type(8))) short bf16x8;
typedef __attribute__((ext_vector_type(4))) float f32x4;

__device__ inline float wave_sum(float x) {
#pragma unroll
  for (int off = 32; off > 0; off >>= 1) x += __shfl_xor(x, off, 64);
  return x;
}

// async global->LDS, 16B per lane, dst = wave-uniform base + lane*16
__device__ inline void gl_lds16(const bf16* g, bf16* l) {
  __builtin_amdgcn_global_load_lds((__attribute__((address_space(1))) void*)g,
                                   (__attribute__((address_space(3))) void*)l,
                                   16, 0, 0);
}

// ---------------- prep: transpose fp32 [K,N] -> bf16 [Npad,K] ----------------
__global__ __launch_bounds__(256) void transpose_bf16(
    const float* __restrict__ src, bf16* __restrict__ dst,
    int K, int N, int Npad, long srcStride, long dstStride) {
  __shared__ float tile[32][33];
  const float* s = src + (size_t)blockIdx.z * srcStride;
  bf16* d = dst + (size_t)blockIdx.z * dstStride;
  int n0 = blockIdx.x * 32, k0 = blockIdx.y * 32;
  int tr = threadIdx.x >> 5, tc = threadIdx.x & 31;
#pragma unroll
  for (int i = 0; i < 4; i++) {
    int k = k0 + tr + i * 8, n = n0 + tc;
    tile[tr + i * 8][tc] = (k < K && n < N) ? s[(size_t)k * N + n] : 0.f;
  }
  __syncthreads();
#pragma unroll
  for (int i = 0; i < 4; i++) {
    int n = n0 + tr + i * 8, k = k0 + tc;
    if (n < Npad && k < K) d[(size_t)n * K + k] = __float2bfloat16(tile[tc][tr + i * 8]);
  }
}

__global__ void concat_bias(const float* __restrict__ bq, const float* __restrict__ bk,
                            const float* __restrict__ bv, float* __restrict__ dst) {
  int i = blockIdx.x * 256 + threadIdx.x;
  if (i >= Ll * 1536) return;
  int l = i / 1536, j = i - l * 1536;
  float v = (j < 512) ? bq[l * 512 + j] : (j < 1024) ? bk[l * 512 + j - 512]
                                                     : bv[l * 512 + j - 1024];
  dst[i] = v;
}

// ---------------- embed ----------------
__global__ void embed_kernel(const int* __restrict__ idx, const int* __restrict__ masks,
                             const float* __restrict__ tok, const float* __restrict__ pos,
                             float* __restrict__ x) {
  int i = blockIdx.x * blockDim.x + threadIdx.x;
  if (i >= NT * Dd) return;
  int d = i & (Dd - 1);
  int row = i >> 9;
  int s = row & (Ss - 1);
  int b = row >> 10;
  int t = idx[b * (Ss + 1) + s];
  float m = (float)masks[row];
  x[i] = (tok[(size_t)t * Dd + d] + pos[s * Dd + d]) * m;
}

// ---------------- LayerNorm: fp32 in, bf16 out; 4 rows/block ----------------
__global__ __launch_bounds__(256) void ln_kernel(const float* __restrict__ x,
                                                 const float* __restrict__ g,
                                                 const float* __restrict__ b,
                                                 bf16* __restrict__ out) {
  int row = blockIdx.x * 4 + (threadIdx.x >> 6);
  int lane = threadIdx.x & 63;
  const float* xr = x + (size_t)row * Dd;
  float vals[8];
  float s = 0.f;
#pragma unroll
  for (int i = 0; i < 8; i++) { vals[i] = xr[lane + i * 64]; s += vals[i]; }
  s = wave_sum(s);
  float mean = s * (1.f / Dd);
  float vs = 0.f;
#pragma unroll
  for (int i = 0; i < 8; i++) { float dd = vals[i] - mean; vs += dd * dd; }
  vs = wave_sum(vs);
  float rstd = rsqrtf(vs * (1.f / Dd) + 1e-5f);
  bf16* orow = out + (size_t)row * Dd;
#pragma unroll
  for (int i = 0; i < 8; i++) {
    int d = lane + i * 64;
    orow[d] = __float2bfloat16((vals[i] - mean) * rstd * g[d] + b[d]);
  }
}

// ---------------- MFMA GEMM (m97 structure) ----------------
// C[M,N] = epilogue( A[M,K]bf16 @ Bt[N,K]bf16^T + bias ) (+resid) -> fp32 or bf16
// 128x128 tile, BK=32, 256 threads (4 waves, each 64x64 via 4x4 of 16x16x32 MFMA)
__global__ __launch_bounds__(256) void mfma_gemm(
    const bf16* __restrict__ A, const bf16* __restrict__ Bt,
    const float* __restrict__ bias, const float* __restrict__ resid,
    float* __restrict__ Cf, bf16* __restrict__ Cb,
    int M, int N, int K, int act) {
  __shared__ bf16 As[128 * 32];
  __shared__ bf16 Bs[128 * 32];
  const int t = threadIdx.x;
  const int w = t >> 6, lane = t & 63;
  const int m0 = blockIdx.y * 128, n0 = blockIdx.x * 128;
  const int rr = lane >> 2;            // 0..15 rows per load inst
  const int cc = (lane & 3) * 8;       // elem col within BK
  const bf16* ap0 = A  + (size_t)(m0 + w * 32 + rr) * K + cc;
  const bf16* ap1 = ap0 + (size_t)16 * K;
  const bf16* bp0 = Bt + (size_t)(n0 + w * 32 + rr) * K + cc;
  const bf16* bp1 = bp0 + (size_t)16 * K;
  bf16* as0 = As + w * 32 * 32;
  bf16* as1 = as0 + 16 * 32;
  bf16* bs0 = Bs + w * 32 * 32;
  bf16* bs1 = bs0 + 16 * 32;
  const int wr = (w >> 1) * 64, wc = (w & 1) * 64;
  const int lm = lane & 15, lk = (lane >> 4) * 8;
  f32x4 acc[4][4];
#pragma unroll
  for (int i = 0; i < 4; i++)
#pragma unroll
    for (int j = 0; j < 4; j++) acc[i][j] = (f32x4){0.f, 0.f, 0.f, 0.f};

  for (int k0 = 0; k0 < K; k0 += 32) {
    __syncthreads();
    gl_lds16(ap0 + k0, as0);
    gl_lds16(ap1 + k0, as1);
    gl_lds16(bp0 + k0, bs0);
    gl_lds16(bp1 + k0, bs1);
    __syncthreads();
    bf16x8 af[4], bg[4];
#pragma unroll
    for (int i = 0; i < 4; i++)
      af[i] = *(const bf16x8*)(As + (wr + i * 16 + lm) * 32 + lk);
#pragma unroll
    for (int j = 0; j < 4; j++)
      bg[j] = *(const bf16x8*)(Bs + (wc + j * 16 + lm) * 32 + lk);
#pragma unroll
    for (int i = 0; i < 4; i++)
#pragma unroll
      for (int j = 0; j < 4; j++)
        acc[i][j] = __builtin_amdgcn_mfma_f32_16x16x32_bf16(af[i], bg[j], acc[i][j], 0, 0, 0);
  }

  const int r4 = (lane >> 4) * 4;
#pragma unroll
  for (int i = 0; i < 4; i++) {
#pragma unroll
    for (int j = 0; j < 4; j++) {
      int col = n0 + wc + j * 16 + lm;
      if (col >= N) continue;
      float bi = bias ? bias[col] : 0.f;
#pragma unroll
      for (int r = 0; r < 4; r++) {
        int row = m0 + wr + i * 16 + r4 + r;
        float v = acc[i][j][r] + bi;
        if (act) v = 0.5f * v * (1.f + erff(v * 0.70710678118654752f));
        if (resid) v += resid[(size_t)row * N + col];
        if (Cf) Cf[(size_t)row * N + col] = v;
        else    Cb[(size_t)row * N + col] = __float2bfloat16(v);
      }
    }
  }
}

// ---------------- flash attention ----------------
// grid (S/64, B*H); 256 threads: 64 q-rows x 4 dim-groups of 16.
// qkv fp32 [NT,1536] (q|k|v), head h at col h*64. Output o bf16 [NT,512].
__global__ __launch_bounds__(256) void attn_kernel(const float* __restrict__ qkv,
                                                   bf16* __restrict__ o) {
  __shared__ float Ks[64][68];
  __shared__ float Vs[64][68];
  __shared__ float Ps[64][68];
  const int t = threadIdx.x;
  const int qi = t >> 2, qq = t & 3, dq = qq * 16;
  const int qt = blockIdx.x;
  const int bh = blockIdx.y;
  const int b = bh >> 3, h = bh & 7;
  const size_t rowbase = (size_t)b * Ss * 1536;
  const int hcol = h * 64;
  const int qrow = qt * 64 + qi;

  float qreg[16];
  {
    const float* qp = qkv + rowbase + (size_t)qrow * 1536 + hcol + dq;
#pragma unroll
    for (int i = 0; i < 16; i++) qreg[i] = qp[i] * INV_SCALE;
  }
  float Oacc[16];
#pragma unroll
  for (int i = 0; i < 16; i++) Oacc[i] = 0.f;
  float m_i = -INFINITY, l_i = 0.f;

  const int lr = t >> 2, lc = (t & 3) * 16;  // staging layout
  for (int c = 0; c <= qt; c++) {
    __syncthreads();
    {
      const float* kp = qkv + rowbase + (size_t)(c * 64 + lr) * 1536 + 512 + hcol + lc;
      const float* vp = qkv + rowbase + (size_t)(c * 64 + lr) * 1536 + 1024 + hcol + lc;
#pragma unroll
      for (int i = 0; i < 4; i++) {
        *(float4*)&Ks[lr][lc + i * 4] = *(const float4*)(kp + i * 4);
        *(float4*)&Vs[lr][lc + i * 4] = *(const float4*)(vp + i * 4);
      }
    }
    __syncthreads();
    // scores: all 4 threads of a row see every s(q,k); keep k%4==qq in regs
    float sreg[16];
    float cm = -INFINITY;
#pragma unroll 4
    for (int kk = 0; kk < 64; kk++) {
      const float4* kr = (const float4*)&Ks[kk][dq];
      float4 p4 = {0.f, 0.f, 0.f, 0.f};
#pragma unroll
      for (int i = 0; i < 4; i++) {
        float4 kv = kr[i];
        p4.x += qreg[i * 4 + 0] * kv.x; p4.y += qreg[i * 4 + 1] * kv.y;
        p4.z += qreg[i * 4 + 2] * kv.z; p4.w += qreg[i * 4 + 3] * kv.w;
      }
      float ps = p4.x + p4.y + p4.z + p4.w;
      ps += __shfl_xor(ps, 1, 64);
      ps += __shfl_xor(ps, 2, 64);
      ps = ((c * 64 + kk) <= qrow) ? ps : -INFINITY;
      if ((kk & 3) == qq) sreg[kk >> 2] = ps;
      cm = fmaxf(cm, ps);
    }
    float m_new = fmaxf(m_i, cm);
    float alpha = __expf(m_i - m_new);   // 0 on first chunk
    float psum = 0.f;
#pragma unroll
    for (int j = 0; j < 16; j++) {
      float p = __expf(sreg[j] - m_new); // 0 for masked
      psum += p;
      Ps[qi][qq + 4 * j] = p;
    }
    psum += __shfl_xor(psum, 1, 64);
    psum += __shfl_xor(psum, 2, 64);
    l_i = l_i * alpha + psum;
    m_i = m_new;
#pragma unroll
    for (int i = 0; i < 16; i++) Oacc[i] *= alpha;
    __syncthreads();  // Ps complete
#pragma unroll 4
    for (int kk = 0; kk < 64; kk++) {
      float p = Ps[qi][kk];
      const float4* vr = (const float4*)&Vs[kk][dq];
#pragma unroll
      for (int i = 0; i < 4; i++) {
        float4 vv = vr[i];
        Oacc[i * 4 + 0] += p * vv.x; Oacc[i * 4 + 1] += p * vv.y;
        Oacc[i * 4 + 2] += p * vv.z; Oacc[i * 4 + 3] += p * vv.w;
      }
    }
  }
  float inv_l = 1.f / l_i;
  bf16* op = o + (size_t)(b * Ss + qrow) * Dd + hcol + dq;
#pragma unroll
  for (int i = 0; i < 16; i++) op[i] = __float2bfloat16(Oacc[i] * inv_l);
}

// ---------------- loss ----------------
__global__ __launch_bounds__(256) void nll_kernel(const float* __restrict__ logits,
                                                  const int* __restrict__ idx,
                                                  const int* __restrict__ masks,
                                                  float* __restrict__ row_nll) {
  __shared__ float red[256];
  int row = blockIdx.x;
  int b = row >> 10, s = row & (Ss - 1);
  const float* lr = logits + (size_t)row * Vv;
  float mx = -INFINITY;
  for (int j = threadIdx.x; j < Vv; j += 256) mx = fmaxf(mx, lr[j]);
  red[threadIdx.x] = mx;
  __syncthreads();
  for (int st = 128; st > 0; st >>= 1) {
    if (threadIdx.x < st) red[threadIdx.x] = fmaxf(red[threadIdx.x], red[threadIdx.x + st]);
    __syncthreads();
  }
  mx = red[0];
  __syncthreads();
  float sum = 0.f;
  for (int j = threadIdx.x; j < Vv; j += 256) sum += __expf(lr[j] - mx);
  red[threadIdx.x] = sum;
  __syncthreads();
  for (int st = 128; st > 0; st >>= 1) {
    if (threadIdx.x < st) red[threadIdx.x] += red[threadIdx.x + st];
    __syncthreads();
  }
  if (threadIdx.x == 0) {
    int target = idx[b * (Ss + 1) + s + 1];
    float nll = logf(red[0]) + mx - lr[target];
    row_nll[row] = nll * (float)masks[row];
  }
}

__global__ __launch_bounds__(256) void loss_reduce_kernel(const float* __restrict__ row_nll,
                                                          float* __restrict__ out_loss) {
  __shared__ float red[256];
  float s = 0.f;
  for (int i = threadIdx.x; i < NT; i += 256) s += row_nll[i];
  red[threadIdx.x] = s;
  __syncthreads();
  for (int st = 128; st > 0; st >>= 1) {
    if (threadIdx.x < st) red[threadIdx.x] += red[threadIdx.x + st];
    __syncthreads();
  }
  if (threadIdx.x == 0) out_loss[0] = red[0] * (1.f / NT);
}

extern "C" void kernel_launch(void* const* d_in, const int* in_sizes, int n_in,
                              void* d_out, int out_size, void* d_ws, size_t ws_size,
                              hipStream_t stream) {
  const int*   idx   = (const int*)d_in[0];
  const int*   masks = (const int*)d_in[1];
  const float* tok   = (const float*)d_in[2];
  const float* pos   = (const float*)d_in[3];
  const float* Wq    = (const float*)d_in[4];
  const float* bq    = (const float*)d_in[5];
  const float* Wk    = (const float*)d_in[6];
  const float* bk    = (const float*)d_in[7];
  const float* Wv    = (const float*)d_in[8];
  const float* bv    = (const float*)d_in[9];
  const float* Wo    = (const float*)d_in[10];
  const float* bo    = (const float*)d_in[11];
  const float* ln1g  = (const float*)d_in[12];
  const float* ln1b  = (const float*)d_in[13];
  const float* W1    = (const float*)d_in[14];
  const float* b1    = (const float*)d_in[15];
  const float* W2    = (const float*)d_in[16];
  const float* b2    = (const float*)d_in[17];
  const float* ln2g  = (const float*)d_in[18];
  const float* ln2b  = (const float*)d_in[19];
  const float* lnfg  = (const float*)d_in[20];
  const float* lnfb  = (const float*)d_in[21];
  const float* headw = (const float*)d_in[22];

  float* out = (float*)d_out;

  // workspace layout (~114 MB)
  char* p = (char*)d_ws;
  auto alloc = [&](size_t bytes) { char* r = p; p += (bytes + 255) & ~255ull; return r; };
  float* x     = (float*)alloc((size_t)NT * Dd * 4);
  bf16*  h     = (bf16*) alloc((size_t)NT * Dd * 2);
  float* qkv   = (float*)alloc((size_t)NT * 1536 * 4);
  bf16*  ob    = (bf16*) alloc((size_t)NT * Dd * 2);
  bf16*  mlp   = (bf16*) alloc((size_t)NT * Dff * 2);
  float* rnll  = (float*)alloc((size_t)NT * 4);
  bf16*  WqkvT = (bf16*) alloc((size_t)Ll * 1536 * 512 * 2);
  bf16*  WoT   = (bf16*) alloc((size_t)Ll * 512 * 512 * 2);
  bf16*  W1T   = (bf16*) alloc((size_t)Ll * 2048 * 512 * 2);
  bf16*  W2T   = (bf16*) alloc((size_t)Ll * 512 * 2048 * 2);
  bf16*  headT = (bf16*) alloc((size_t)Vpad * 512 * 2);
  float* bqkvc = (float*)alloc((size_t)Ll * 1536 * 4);

  const long DD = (long)Dd * Dd;
  // prep: weight transpose+convert
  transpose_bf16<<<dim3(16, 16, Ll), 256, 0, stream>>>(Wq, WqkvT,               512, 512, 512,  DD, 1536L * 512);
  transpose_bf16<<<dim3(16, 16, Ll), 256, 0, stream>>>(Wk, WqkvT + 512 * 512,   512, 512, 512,  DD, 1536L * 512);
  transpose_bf16<<<dim3(16, 16, Ll), 256, 0, stream>>>(Wv, WqkvT + 1024 * 512,  512, 512, 512,  DD, 1536L * 512);
  transpose_bf16<<<dim3(16, 16, Ll), 256, 0, stream>>>(Wo, WoT,                 512, 512, 512,  DD, DD);
  transpose_bf16<<<dim3(64, 16, Ll), 256, 0, stream>>>(W1, W1T,                 512, 2048, 2048, (long)512 * 2048, (long)2048 * 512);
  transpose_bf16<<<dim3(16, 64, Ll), 256, 0, stream>>>(W2, W2T,                 2048, 512, 512, (long)2048 * 512, (long)512 * 2048);
  transpose_bf16<<<dim3(Vpad / 32, 16, 1), 256, 0, stream>>>(headw, headT,      512, Vv, Vpad,  0, 0);
  concat_bias<<<(Ll * 1536 + 255) / 256, 256, 0, stream>>>(bq, bk, bv, bqkvc);

  embed_kernel<<<(NT * Dd + 255) / 256, 256, 0, stream>>>(idx, masks, tok, pos, x);

  for (int l = 0; l < Ll; l++) {
    ln_kernel<<<NT / 4, 256, 0, stream>>>(x, ln1g + (size_t)l * Dd, ln1b + (size_t)l * Dd, h);
    mfma_gemm<<<dim3(12, 16), 256, 0, stream>>>(h, WqkvT + (size_t)l * 1536 * 512,
        bqkvc + (size_t)l * 1536, nullptr, qkv, nullptr, NT, 1536, 512, 0);
    attn_kernel<<<dim3(Ss / 64, Bb * Hh), 256, 0, stream>>>(qkv, ob);
    mfma_gemm<<<dim3(4, 16), 256, 0, stream>>>(ob, WoT + (size_t)l * DD,
        bo + (size_t)l * Dd, x, x, nullptr, NT, 512, 512, 0);
    ln_kernel<<<NT / 4, 256, 0, stream>>>(x, ln2g + (size_t)l * Dd, ln2b + (size_t)l * Dd, h);
    mfma_gemm<<<dim3(16, 16), 256, 0, stream>>>(h, W1T + (size_t)l * Dff * Dd,
        b1 + (size_t)l * Dff, nullptr, nullptr, mlp, NT, 2048, 512, 1);
    mfma_gemm<<<dim3(4, 16), 256, 0, stream>>>(mlp, W2T + (size_t)l * Dff * Dd,
        b2 + (size_t)l * Dd, x, x, nullptr, NT, 512, 2048, 0);
  }

  ln_kernel<<<NT / 4, 256, 0, stream>>>(x, lnfg, lnfb, h);
  mfma_gemm<<<dim3(Vpad / 128, 16), 256, 0, stream>>>(h, headT, nullptr, nullptr,
      out, nullptr, NT, Vv, 512, 0);

  nll_kernel<<<NT, 256, 0, stream>>>(out, idx, masks, rnll);
  loss_reduce_kernel<<<1, 256, 0, stream>>>(rnll, out + (size_t)NT * Vv);
}